// Round 1
// baseline (35.883 us; speedup 1.0000x reference)
//
#include <hip/hip_runtime.h>

// LocalSelfAttention: bs=4, h=12, s=4096, d=64, BLOCK=64 -> 3072 independent
// 64x64x64 block-attention problems. fp32 in/out, no padding (4096 % 64 == 0).
// Memory-bound: ~201 MB HBM -> ~32 us floor. MFMA (bf16 hi/lo split) for QK^T
// and PV, everything else hidden under the stream.

typedef __attribute__((ext_vector_type(8))) short bf16x8;   // 8 bf16 = 4 VGPR
typedef __attribute__((ext_vector_type(4))) float f32x4;    // MFMA 16x16 acc
typedef __attribute__((ext_vector_type(4))) unsigned short us4; // 8B LDS store

#define MFMA16(a, b, c) __builtin_amdgcn_mfma_f32_16x16x32_bf16((a), (b), (c), 0, 0, 0)
// XOR swizzle (guide §6 G4): row-major [64][64] bf16 has 128B row stride ->
// column reads are 16-way bank conflicts without this.
#define SWZ(byteoff, row) ((byteoff) ^ (((row) & 7) << 4))

static __device__ __forceinline__ unsigned short f2bf(float x) {
    union { float f; unsigned int u; } v; v.f = x;
    unsigned int r = v.u + 0x7fffu + ((v.u >> 16) & 1u);   // RNE
    return (unsigned short)(r >> 16);
}
static __device__ __forceinline__ float bf2f(unsigned short b) {
    union { float f; unsigned int u; } v; v.u = ((unsigned int)b) << 16;
    return v.f;
}

// grid: one workgroup (256 thr = 4 waves) per (b, h, block). Each wave owns a
// 16-query strip. Computes S^T = K·Q^T so softmax is 2 shuffles per row.
__global__ __launch_bounds__(256) void lsa_kernel(
    const float* __restrict__ Q, const float* __restrict__ K,
    const float* __restrict__ V, const float* __restrict__ M,
    float* __restrict__ O)
{
    __shared__ unsigned short Kh[4096];   // K block bf16 hi   [key][d]
    __shared__ unsigned short Kl[4096];   // K block bf16 lo
    __shared__ unsigned short VT[4096];   // V block bf16, transposed: [d][key]
    __shared__ unsigned short P [4096];   // probs bf16        [q][key]
    __shared__ float maskv[64];           // mask values for this block's keys

    const int tid = threadIdx.x;
    const int gid = blockIdx.x;                // (b*12 + h)*64 + blk
    const size_t base = (size_t)gid * 4096;    // contiguous 64x64 fp32 block

    const int lane = tid & 63;
    const int wv   = tid >> 6;      // wave id = query strip (16 rows each)
    const int cc   = lane & 15;
    const int gg   = lane >> 4;
    const int qrow = wv * 16 + cc;  // this lane's query row (A/B frag row)

    // ---- issue all global loads first (K, V staging + Q fragments) ----
    const float4* Kg = (const float4*)(K + base);
    const float4* Vg = (const float4*)(V + base);
    float4 kv[4], vv[4];
#pragma unroll
    for (int it = 0; it < 4; ++it) {
        int i = tid + it * 256;
        kv[it] = Kg[i];
        vv[it] = Vg[i];
    }
    // Q fragment direct from global: wave-level pattern = rows wv*16..+16,
    // 128B contiguous halves -> fully coalesced. Skips LDS entirely.
    bf16x8 qfh[2], qfl[2];
#pragma unroll
    for (int s = 0; s < 2; ++s) {
        const float* qp = Q + base + (size_t)qrow * 64 + s * 32 + gg * 8;
        float4 f0 = *(const float4*)qp;
        float4 f1 = *(const float4*)(qp + 4);
        float f[8] = {f0.x, f0.y, f0.z, f0.w, f1.x, f1.y, f1.z, f1.w};
        bf16x8 h, l;
#pragma unroll
        for (int j = 0; j < 8; ++j) {
            unsigned short hb = f2bf(f[j]);
            h[j] = (short)hb;
            l[j] = (short)f2bf(f[j] - bf2f(hb));   // exact residual
        }
        qfh[s] = h; qfl[s] = l;
    }
    if (tid < 64) {
        int b = gid / 768;          // / (h*nb) = / (12*64)
        int blk = gid & 63;
        maskv[tid] = M[(size_t)b * 4096 + blk * 64 + tid];
    }

    // ---- convert + store K (hi/lo) and V^T into LDS ----
#pragma unroll
    for (int it = 0; it < 4; ++it) {
        int i = tid + it * 256;     // float4 index 0..1023
        int row = i >> 4;           // 16 float4 per 64-float row
        int cb  = (i & 15) * 8;     // byte col (4 bf16 = 8B)
        {
            float4 x = kv[it];
            us4 h, l;
            unsigned short hb;
            hb = f2bf(x.x); h.x = hb; l.x = f2bf(x.x - bf2f(hb));
            hb = f2bf(x.y); h.y = hb; l.y = f2bf(x.y - bf2f(hb));
            hb = f2bf(x.z); h.z = hb; l.z = f2bf(x.z - bf2f(hb));
            hb = f2bf(x.w); h.w = hb; l.w = f2bf(x.w - bf2f(hb));
            int by = SWZ(row * 128 + cb, row);
            *(us4*)((char*)Kh + by) = h;
            *(us4*)((char*)Kl + by) = l;
        }
        {
            float4 x = vv[it];
            int key = row, dbase = (i & 15) * 4;
            float xs[4] = {x.x, x.y, x.z, x.w};
#pragma unroll
            for (int dj = 0; dj < 4; ++dj) {
                int d = dbase + dj;
                *(unsigned short*)((char*)VT + SWZ(d * 128 + key * 2, d)) = f2bf(xs[dj]);
            }
        }
    }
    __syncthreads();

    // ---- scores: S^T[key][q] = sum_d K[key][d] * Q[q][d]  (hi/lo 3-term) ----
    // C/D layout (m89-verified): col = lane&15 = q, row = g*4+reg = key-local.
    float sc[16];
#pragma unroll
    for (int kt = 0; kt < 4; ++kt) {
        f32x4 acc = {0.f, 0.f, 0.f, 0.f};
        int krow = kt * 16 + cc;
#pragma unroll
        for (int s = 0; s < 2; ++s) {
            int by = SWZ(krow * 128 + s * 64 + gg * 16, krow);
            bf16x8 ah = *(bf16x8*)((char*)Kh + by);
            bf16x8 al = *(bf16x8*)((char*)Kl + by);
            acc = MFMA16(ah, qfh[s], acc);
            acc = MFMA16(ah, qfl[s], acc);
            acc = MFMA16(al, qfh[s], acc);
        }
#pragma unroll
        for (int r = 0; r < 4; ++r) sc[kt * 4 + r] = acc[r];
    }

    // ---- mask + softmax over keys (this lane: one query, 16 of 64 keys) ----
    float mx = -3.0e38f;
#pragma unroll
    for (int kt = 0; kt < 4; ++kt)
#pragma unroll
        for (int r = 0; r < 4; ++r) {
            int key = kt * 16 + gg * 4 + r;
            float sv = sc[kt * 4 + r] + (maskv[key] == 0.f ? -10000.f : 0.f);
            sc[kt * 4 + r] = sv;
            mx = fmaxf(mx, sv);
        }
    mx = fmaxf(mx, __shfl_xor(mx, 16));
    mx = fmaxf(mx, __shfl_xor(mx, 32));
    float sum = 0.f;
#pragma unroll
    for (int i = 0; i < 16; ++i) { sc[i] = __expf(sc[i] - mx); sum += sc[i]; }
    sum += __shfl_xor(sum, 16);
    sum += __shfl_xor(sum, 32);
    float inv = (maskv[qrow] == 0.f ? 0.f : 1.f) / sum;   // q_removed -> 0 row

    // ---- write P[q][key] (bf16, swizzled); keys g*4+r are contiguous ----
#pragma unroll
    for (int kt = 0; kt < 4; ++kt) {
        us4 pw;
        pw.x = f2bf(sc[kt * 4 + 0] * inv);
        pw.y = f2bf(sc[kt * 4 + 1] * inv);
        pw.z = f2bf(sc[kt * 4 + 2] * inv);
        pw.w = f2bf(sc[kt * 4 + 3] * inv);
        *(us4*)((char*)P + SWZ(qrow * 128 + kt * 32 + gg * 8, qrow)) = pw;
    }
    __syncthreads();   // cheap safety: P cross-lane visibility before PV reads

    // ---- O = P · V  via A=P (row=q), B=V^T rows (contiguous keys) ----
    bf16x8 pf[2];
#pragma unroll
    for (int s = 0; s < 2; ++s)
        pf[s] = *(bf16x8*)((char*)P + SWZ(qrow * 128 + s * 64 + gg * 16, qrow));

    float* Ob = O + base;
#pragma unroll
    for (int dt = 0; dt < 4; ++dt) {
        f32x4 o = {0.f, 0.f, 0.f, 0.f};
#pragma unroll
        for (int s = 0; s < 2; ++s) {
            int vr = dt * 16 + cc;
            bf16x8 vb = *(bf16x8*)((char*)VT + SWZ(vr * 128 + s * 64 + gg * 16, vr));
            o = MFMA16(pf[s], vb, o);
        }
#pragma unroll
        for (int r = 0; r < 4; ++r) {
            int q = wv * 16 + gg * 4 + r;   // D-layout row -> query
            Ob[q * 64 + dt * 16 + cc] = o[r];
        }
    }
}

extern "C" void kernel_launch(void* const* d_in, const int* in_sizes, int n_in,
                              void* d_out, int out_size, void* d_ws, size_t ws_size,
                              hipStream_t stream) {
    const float* Q = (const float*)d_in[0];
    const float* K = (const float*)d_in[1];
    const float* V = (const float*)d_in[2];
    const float* M = (const float*)d_in[3];
    float* O = (float*)d_out;
    // bs=4, h=12, s=4096, d=64, BLOCK=64 -> 3072 blocks of 64x64 fp32
    int grid = in_sizes[0] / 4096;   // = 3072
    lsa_kernel<<<grid, 256, 0, stream>>>(Q, K, V, M, O);
}